// Round 9
// baseline (5090.997 us; speedup 1.0000x reference)
//
#include <hip/hip_runtime.h>

#define NB 4
#define NPT 32768
#define HPT 16384         // points per half-cloud
#define CIN 128
#define COUT 256
#define NS 2048
#define THR 1024
#define PPT 16            // points per thread (HPT / THR)

// ws float-offset layout
#define WS_G 0            // 128*128 Gram
#define WS_FSUM 16384     // 128 column sums
#define WS_SLOT 16512     // 32 x uint64 sync slots (= 64 floats)
#define WS_GSCALE 16576   // 256
#define WS_GBIAS 16832    // 256
#define WS_IDX 17088      // 8192 ints

// d_out float-offset layout
#define OUT_COORD 0
#define OUT_FEAT 24576
#define OUT_OFFS 2121728

// Established rounds 1-8:
//  * VGPR budget pinned by toolchain occupancy formula; design under it.
//  * WRITE_SIZE ~66 MB = Gram's 2.1M memory-side atomics. Expected.
//  * agent-scope atomics are serviced memory-side (~800 cyc RT); rocprof
//    inflates spin-poll kernels (r8: profiled 5600 > unprofiled total 4746)
//    -- compare rounds on unprofiled totals only.
//  * r8's 4-way exchange: poll gates on slowest-of-4 + all-or-retry rounds
//    -> ~2.2 us/iter floor. This round: 2 blocks x 1024 threads per cloud.
//    One partner slot to poll, skew of 2 not 4; state still all-registers
//    (48 coord + 16 dist + temps ~ 90 regs at 16 waves/CU -> 128 cap).
//  * tagged monotone key it<<48 | dbits<<15 | (32767-gidx): stale values
//    lose atomicMax automatically; slot reuse at parity distance 2 is safe
//    (store(it+2) happens-after partner consumed (it), same induction).
__global__ __launch_bounds__(THR) void fused1(
    const float* __restrict__ coord, const float* __restrict__ feat,
    float* __restrict__ wsf, int* __restrict__ wsi,
    unsigned long long* __restrict__ slots)
{
  __shared__ unsigned long long s_key[2];
  __shared__ float s_fs[8][128];

  const int bid = blockIdx.x;
  const int t = threadIdx.x;
  const bool is_fps = (bid < 12) && ((bid & 7) < 4);

  if (is_fps) {
    // ---------------- FPS: cloud cl, half h ----------------
    const int cl = bid & 3;
    const int h = bid >> 3;                    // 0/1; {cl, cl+8} same XCD (%8)
    const int gbase = h * HPT;
    const float* xyz = coord + (size_t)cl * NPT * 3;
    int* idx_out = wsi + cl * NS;
    unsigned long long* slot = slots + cl * 4; // [par][h]

    float px[PPT], py[PPT], pz[PPT], dv[PPT];
#pragma unroll
    for (int j = 0; j < PPT; ++j) {
      int p = gbase + j * THR + t;
      px[j] = xyz[p * 3 + 0];
      py[j] = xyz[p * 3 + 1];
      pz[j] = xyz[p * 3 + 2];
      dv[j] = 1e10f;
    }
    if (t == 0) {
      if (h == 0) idx_out[0] = 0;              // every cloud writes sample 0
      s_key[0] = s_key[1] = 0ull;              // tag 0 < any it>=1
    }
    float cx = xyz[0], cy = xyz[1], cz = xyz[2];   // same-address broadcast
    __syncthreads();

    const int lane = t & 63;
    for (int it = 1; it < NS; ++it) {
      const int par = it & 1;
      const unsigned long long utag = (unsigned long long)it;
      float bd = -1.f;
      int bj = 0;
      // exact numpy-f32 distance: plain muls (asm blocks fma contraction),
      // (sx+sy)+sz, v_min_f32 update; argmax tracked inline (strict > keeps
      // lowest j = lowest global index within this thread's stride).
#pragma unroll
      for (int j = 0; j < PPT; ++j) {
        float dx = px[j] - cx, dy = py[j] - cy, dz = pz[j] - cz;
        float sx = dx * dx, sy = dy * dy, sz = dz * dz;
        asm volatile("" : "+v"(sx), "+v"(sy), "+v"(sz));
        float nd = fminf(dv[j], (sx + sy) + sz);
        dv[j] = nd;
        if (nd > bd) { bd = nd; bj = j; }
      }
      const int gidx = gbase + bj * THR + t;
      // tagged monotone key: bigger dist wins, tie -> lower idx (np.argmax)
      const unsigned long long tkey =
          (utag << 48) |
          ((unsigned long long)(unsigned)__float_as_int(bd) << 15) |
          (unsigned)(32767 - gidx);
      unsigned long long wkey = tkey;
#pragma unroll
      for (int o = 32; o > 0; o >>= 1) {
        unsigned long long ok = __shfl_xor(wkey, o, 64);
        wkey = ok > wkey ? ok : wkey;
      }
      if (lane == 0) atomicMax(&s_key[par], wkey);
      __syncthreads();                         // the ONLY barrier per iter
      const unsigned long long skey = s_key[par];
      if (tkey == skey)                        // unique winner thread
        __hip_atomic_store(&slot[par * 2 + h], skey,
                           __ATOMIC_RELAXED, __HIP_MEMORY_SCOPE_AGENT);
      unsigned long long v;
      do {                                     // single partner slot poll
        v = __hip_atomic_load(&slot[par * 2 + (1 - h)],
                              __ATOMIC_RELAXED, __HIP_MEMORY_SCOPE_AGENT);
      } while ((v >> 48) != utag);
      const unsigned long long best = v > skey ? v : skey;
      const int widx = 32767 - (int)(best & 0x7fff);
      if (h == 0 && t == 0) idx_out[it] = widx;
      cx = xyz[widx * 3 + 0];                  // same-address broadcast load
      cy = xyz[widx * 3 + 1];
      cz = xyz[widx * 3 + 2];
    }
  } else {
    // non-FPS linear index: bids 4-7 -> g 0-3; 12-15 -> g 4-7; 16-79 -> 8-71
    const int g = (bid < 8) ? (bid - 4) : (bid - 8);
    if (g < 64) {
      // ------- Gram partial: G += chunk^T chunk (2048 rows per block) -------
      const int tt = t & 511, sub = t >> 9;
      const float* fr = feat + ((size_t)g * 2048 + sub * 1024) * CIN;
      const int ti = (tt & 31) * 4;
      const int tj = (tt >> 5) * 8;
      float acc[4][8];
#pragma unroll
      for (int a = 0; a < 4; ++a)
#pragma unroll
        for (int b2 = 0; b2 < 8; ++b2) acc[a][b2] = 0.f;
#pragma unroll 4
      for (int r = 0; r < 1024; ++r) {
        const float* rowp = fr + r * CIN;
        float4 a4 = *(const float4*)(rowp + ti);
        float4 b4 = *(const float4*)(rowp + tj);
        float4 b5 = *(const float4*)(rowp + tj + 4);
        float av[4] = {a4.x, a4.y, a4.z, a4.w};
        float bv[8] = {b4.x, b4.y, b4.z, b4.w, b5.x, b5.y, b5.z, b5.w};
#pragma unroll
        for (int a = 0; a < 4; ++a)
#pragma unroll
          for (int b2 = 0; b2 < 8; ++b2) acc[a][b2] += av[a] * bv[b2];
      }
      float* G = wsf + WS_G;
#pragma unroll
      for (int a = 0; a < 4; ++a)
#pragma unroll
        for (int b2 = 0; b2 < 8; ++b2)
          atomicAdd(&G[(ti + a) * CIN + (tj + b2)], acc[a][b2]);
    } else {
      // ---------------- column sums of feat ----------------
      const int fb = g - 64;              // 0..7
      const size_t base = (size_t)fb * 16384;
      const int c = t & 127, rg = t >> 7; // 0..7
      float s = 0.f;
      for (int r = rg; r < 16384; r += 8)
        s += feat[(base + r) * CIN + c];
      s_fs[rg][c] = s;
      __syncthreads();
      if (t < 128) {
        float v = s_fs[0][t] + s_fs[1][t] + s_fs[2][t] + s_fs[3][t] +
                  s_fs[4][t] + s_fs[5][t] + s_fs[6][t] + s_fs[7][t];
        atomicAdd(&wsf[WS_FSUM + t], v);
      }
    }
  }
}

// mean[c] = (fsum . W[c]) / M ; E[x^2][c] = W[c]^T G W[c] / M
__global__ __launch_bounds__(128) void finalize_k(
    const float* __restrict__ W, const float* __restrict__ gamma,
    const float* __restrict__ beta, float* __restrict__ wsf)
{
  const int c = blockIdx.x, i = threadIdx.x;
  const float* G = wsf + WS_G;
  const float* fsum = wsf + WS_FSUM;
  const float* Gi = G + i * CIN;
  const float* Wc = W + c * CIN;
  float td = 0.f;
#pragma unroll 8
  for (int j = 0; j < CIN; j += 4) {
    float4 g4 = *(const float4*)(Gi + j);
    float4 w4 = *(const float4*)(Wc + j);
    td += g4.x * w4.x + g4.y * w4.y + g4.z * w4.z + g4.w * w4.w;
  }
  const float wci = Wc[i];
  float q = wci * td;
  float m = fsum[i] * wci;
#pragma unroll
  for (int o = 32; o > 0; o >>= 1) {
    q += __shfl_xor(q, o, 64);
    m += __shfl_xor(m, o, 64);
  }
  __shared__ float sq[2], sm[2];
  if ((i & 63) == 0) { sq[i >> 6] = q; sm[i >> 6] = m; }
  __syncthreads();
  if (i == 0) {
    const float inv_m = 1.f / 131072.f;
    float mean = (sm[0] + sm[1]) * inv_m;
    float e2 = (sq[0] + sq[1]) * inv_m;
    float var = e2 - mean * mean;
    float rstd = rsqrtf(var + 1e-5f);
    float gs = gamma[c] * rstd;
    wsf[WS_GSCALE + c] = gs;
    wsf[WS_GBIAS + c] = beta[c] - mean * gs;
  }
}

// recompute x rows only at sampled indices, normalize + relu, gather coords
__global__ __launch_bounds__(256) void gather_k(
    const float* __restrict__ coord, const float* __restrict__ feat,
    const float* __restrict__ W, const float* __restrict__ wsf,
    const int* __restrict__ wsi, float* __restrict__ out)
{
  const int p = blockIdx.x, t = threadIdx.x;
  const int b = p >> 11;
  const int idx = wsi[p];
  const size_t row = (size_t)b * NPT + idx;
  __shared__ float lf[CIN];
  if (t < CIN) lf[t] = feat[row * CIN + t];
  __syncthreads();
  const float* Wc = W + t * CIN;
  float acc = 0.f;
#pragma unroll 8
  for (int k = 0; k < CIN; k += 4) {
    float4 w4 = *(const float4*)(Wc + k);
    acc += lf[k] * w4.x + lf[k + 1] * w4.y + lf[k + 2] * w4.z + lf[k + 3] * w4.w;
  }
  float y = fmaxf(fmaf(acc, wsf[WS_GSCALE + t], wsf[WS_GBIAS + t]), 0.f);
  out[OUT_FEAT + (size_t)p * COUT + t] = y;
  if (t < 3) out[OUT_COORD + p * 3 + t] = coord[row * 3 + t];
  if (p == 0 && t < 4) out[OUT_OFFS + t] = (float)((t + 1) * NS);
}

extern "C" void kernel_launch(void* const* d_in, const int* in_sizes, int n_in,
                              void* d_out, int out_size, void* d_ws, size_t ws_size,
                              hipStream_t stream)
{
  const float* coord = (const float*)d_in[0];
  const float* feat  = (const float*)d_in[1];
  // d_in[2] = offset (implied by constants)
  const float* W     = (const float*)d_in[3];
  const float* gamma = (const float*)d_in[4];
  const float* beta  = (const float*)d_in[5];
  float* wsf = (float*)d_ws;
  int* wsi = (int*)(wsf + WS_IDX);
  unsigned long long* slots = (unsigned long long*)(wsf + WS_SLOT);
  float* out = (float*)d_out;

  // zero Gram + colsum accumulators AND sync slots (kills stale tags
  // across graph replays; stream-ordered before fused1)
  hipMemsetAsync(d_ws, 0, (WS_SLOT + 64) * sizeof(float), stream);

  fused1<<<80, THR, 0, stream>>>(coord, feat, wsf, wsi, slots);
  finalize_k<<<COUT, 128, 0, stream>>>(W, gamma, beta, wsf);
  gather_k<<<NB * NS, 256, 0, stream>>>(coord, feat, W, wsf, wsi, out);
}